// Round 1
// baseline (1731.618 us; speedup 1.0000x reference)
//
#include <hip/hip_runtime.h>
#include <math.h>

// Problem constants (fixed by the reference): B=4, S=2048, D=1024.
#define BATCH 4
#define SEQ   2048
#define DIM   1024

__device__ __forceinline__ float gmask(int k) {
    // exp(-0.5*((k - S/2)/(S/4))^2), S=2048 -> center 1024, sigma 512
    float t = ((float)k - 1024.0f) * (1.0f / 512.0f);
    return expf(-0.5f * t * t);
}

// C[M,N] = scale * (A @ op(B))  [* gaussmask(col)]  [+ bias(col)]
//   BT=true : B is [N,K] row-major (op(B)=B^T), read along K
//   BT=false: B is [K,N] row-major
// 128x128 tile, BK=16, 256 threads, 8x8 microtile per thread.
// Optional batch strides via blockIdx.z.
template <bool BT, bool MASK, bool BIAS>
__global__ __launch_bounds__(256) void gemm128(
    const float* __restrict__ A, const float* __restrict__ Bm,
    const float* __restrict__ bias, float* __restrict__ C,
    int M, int N, int K, float scale,
    long strideA, long strideB, long strideC)
{
    const int bz = blockIdx.z;
    A += (long)bz * strideA;
    Bm += (long)bz * strideB;
    C += (long)bz * strideC;

    __shared__ float As[16][132];   // As[k][m], pad 132 keeps b128 reads aligned
    __shared__ float Bs[16][132];   // Bs[k][n]

    const int tid = threadIdx.x;
    const int tx = tid & 15;        // n-dir
    const int ty = tid >> 4;        // m-dir
    const int m0 = blockIdx.y * 128;
    const int n0 = blockIdx.x * 128;

    float acc[8][8];
#pragma unroll
    for (int i = 0; i < 8; ++i)
#pragma unroll
        for (int j = 0; j < 8; ++j) acc[i][j] = 0.0f;

    for (int k0 = 0; k0 < K; k0 += 16) {
        // ---- load A tile [128][16], transpose into As[k][m]
#pragma unroll
        for (int i = 0; i < 2; ++i) {
            int f = tid + 256 * i;           // 0..511
            int row = f >> 2;                // 0..127
            int seg = f & 3;                 // 0..3 (4 floats each)
            float4 v = *(const float4*)(A + (long)(m0 + row) * K + k0 + seg * 4);
            As[seg * 4 + 0][row] = v.x;
            As[seg * 4 + 1][row] = v.y;
            As[seg * 4 + 2][row] = v.z;
            As[seg * 4 + 3][row] = v.w;
        }
        // ---- load B tile
        if (BT) {
#pragma unroll
            for (int i = 0; i < 2; ++i) {
                int f = tid + 256 * i;
                int row = f >> 2;            // n index 0..127
                int seg = f & 3;
                float4 v = *(const float4*)(Bm + (long)(n0 + row) * K + k0 + seg * 4);
                Bs[seg * 4 + 0][row] = v.x;
                Bs[seg * 4 + 1][row] = v.y;
                Bs[seg * 4 + 2][row] = v.z;
                Bs[seg * 4 + 3][row] = v.w;
            }
        } else {
#pragma unroll
            for (int i = 0; i < 2; ++i) {
                int f = tid + 256 * i;       // 0..511 -> 16 rows x 32 float4
                int r = f >> 5;              // k row 0..15
                int c = f & 31;              // float4 col
                float4 v = *(const float4*)(Bm + (long)(k0 + r) * N + n0 + c * 4);
                *(float4*)&Bs[r][c * 4] = v;
            }
        }
        __syncthreads();

#pragma unroll
        for (int kk = 0; kk < 16; ++kk) {
            float a[8], b[8];
            *(float4*)&a[0] = *(const float4*)&As[kk][ty * 8];
            *(float4*)&a[4] = *(const float4*)&As[kk][ty * 8 + 4];
            *(float4*)&b[0] = *(const float4*)&Bs[kk][tx * 8];
            *(float4*)&b[4] = *(const float4*)&Bs[kk][tx * 8 + 4];
#pragma unroll
            for (int i = 0; i < 8; ++i)
#pragma unroll
                for (int j = 0; j < 8; ++j)
                    acc[i][j] = fmaf(a[i], b[j], acc[i][j]);
        }
        __syncthreads();
    }

    // ---- epilogue
#pragma unroll
    for (int i = 0; i < 8; ++i) {
        long m = m0 + ty * 8 + i;
        float* crow = C + m * (long)N + n0 + tx * 8;
#pragma unroll
        for (int j0 = 0; j0 < 8; j0 += 4) {
            int n = n0 + tx * 8 + j0;
            float4 v;
            v.x = acc[i][j0 + 0] * scale;
            v.y = acc[i][j0 + 1] * scale;
            v.z = acc[i][j0 + 2] * scale;
            v.w = acc[i][j0 + 3] * scale;
            if (MASK) {
                v.x *= gmask(n + 0);
                v.y *= gmask(n + 1);
                v.z *= gmask(n + 2);
                v.w *= gmask(n + 3);
            }
            if (BIAS) {
                v.x += bias[n + 0];
                v.y += bias[n + 1];
                v.z += bias[n + 2];
                v.w += bias[n + 3];
            }
            *(float4*)(crow + j0) = v;
        }
    }
}

// In-place row softmax over rows of length SEQ (=2048 = 8*256).
// grid: (rows_per_batch, nb); P row base = z*strideB + x*SEQ
__global__ __launch_bounds__(256) void softmax_rows(
    float* __restrict__ P, long strideB)
{
    long base = (long)blockIdx.y * strideB + (long)blockIdx.x * SEQ;
    const int tid = threadIdx.x;

    float v[8];
    float mx = -1e30f;
#pragma unroll
    for (int i = 0; i < 8; ++i) {
        v[i] = P[base + i * 256 + tid];
        mx = fmaxf(mx, v[i]);
    }
#pragma unroll
    for (int off = 32; off > 0; off >>= 1)
        mx = fmaxf(mx, __shfl_down(mx, off));
    __shared__ float redm[4];
    if ((tid & 63) == 0) redm[tid >> 6] = mx;
    __syncthreads();
    mx = fmaxf(fmaxf(redm[0], redm[1]), fmaxf(redm[2], redm[3]));

    float s = 0.0f;
#pragma unroll
    for (int i = 0; i < 8; ++i) {
        v[i] = expf(v[i] - mx);
        s += v[i];
    }
#pragma unroll
    for (int off = 32; off > 0; off >>= 1)
        s += __shfl_down(s, off);
    __shared__ float reds[4];
    if ((tid & 63) == 0) reds[tid >> 6] = s;
    __syncthreads();
    s = reds[0] + reds[1] + reds[2] + reds[3];
    float inv = 1.0f / s;
#pragma unroll
    for (int i = 0; i < 8; ++i)
        P[base + i * 256 + tid] = v[i] * inv;
}

extern "C" void kernel_launch(void* const* d_in, const int* in_sizes, int n_in,
                              void* d_out, int out_size, void* d_ws, size_t ws_size,
                              hipStream_t stream)
{
    const float* x  = (const float*)d_in[0];
    const float* Wq = (const float*)d_in[1];
    const float* bq = (const float*)d_in[2];
    const float* Wk = (const float*)d_in[3];
    const float* bk = (const float*)d_in[4];
    const float* Wv = (const float*)d_in[5];
    const float* bv = (const float*)d_in[6];
    const float* Wo = (const float*)d_in[7];
    const float* bo = (const float*)d_in[8];
    float* out = (float*)d_out;

    const int Bn = BATCH, S = SEQ, D = DIM;
    const long MD = (long)Bn * S * D;   // 8M elements
    float* Q  = (float*)d_ws;
    float* Km = Q + MD;
    float* V  = Km + MD;
    float* O1 = V + MD;
    float* Sc = O1 + MD;

    // batched scores need B*S*S extra floats; per-batch only S*S
    const size_t need_batched  = (size_t)(4 * MD + (long)Bn * S * S) * sizeof(float);
    const bool batched = ws_size >= need_batched;

    dim3 blk(256);

    // QKV projections: [B*S, D] = x @ W^T + b
    gemm128<true, false, true><<<dim3(D / 128, (Bn * S) / 128, 1), blk, 0, stream>>>(
        x, Wq, bq, Q, Bn * S, D, D, 1.0f, 0, 0, 0);
    gemm128<true, false, true><<<dim3(D / 128, (Bn * S) / 128, 1), blk, 0, stream>>>(
        x, Wk, bk, Km, Bn * S, D, D, 1.0f, 0, 0, 0);
    gemm128<true, false, true><<<dim3(D / 128, (Bn * S) / 128, 1), blk, 0, stream>>>(
        x, Wv, bv, V, Bn * S, D, D, 1.0f, 0, 0, 0);

    const float sc = 0.03125f;  // 1/sqrt(1024)
    if (batched) {
        // scores for all batches at once
        gemm128<true, true, false><<<dim3(S / 128, S / 128, Bn), blk, 0, stream>>>(
            Q, Km, nullptr, Sc, S, S, D, sc, (long)S * D, (long)S * D, (long)S * S);
        softmax_rows<<<dim3(S, Bn), blk, 0, stream>>>(Sc, (long)S * S);
        gemm128<false, false, false><<<dim3(D / 128, S / 128, Bn), blk, 0, stream>>>(
            Sc, V, nullptr, O1, S, D, S, 1.0f, (long)S * S, (long)S * D, (long)S * D);
    } else {
        for (int b = 0; b < Bn; ++b) {
            const float* Qb = Q + (long)b * S * D;
            const float* Kb = Km + (long)b * S * D;
            const float* Vb = V + (long)b * S * D;
            float* Ob = O1 + (long)b * S * D;
            gemm128<true, true, false><<<dim3(S / 128, S / 128, 1), blk, 0, stream>>>(
                Qb, Kb, nullptr, Sc, S, S, D, sc, 0, 0, 0);
            softmax_rows<<<dim3(S, 1), blk, 0, stream>>>(Sc, 0);
            gemm128<false, false, false><<<dim3(D / 128, S / 128, 1), blk, 0, stream>>>(
                Sc, Vb, nullptr, Ob, S, D, S, 1.0f, 0, 0, 0);
        }
    }

    // output projection: out = O1 @ Wo^T + bo
    gemm128<true, false, true><<<dim3(D / 128, (Bn * S) / 128, 1), blk, 0, stream>>>(
        O1, Wo, bo, out, Bn * S, D, D, 1.0f, 0, 0, 0);
}

// Round 2
// 489.019 us; speedup vs baseline: 3.5410x; 3.5410x over previous
//
#include <hip/hip_runtime.h>
#include <math.h>

#define SEQ   2048
#define DIM   1024

typedef __attribute__((ext_vector_type(8))) short short8;
typedef __attribute__((ext_vector_type(4))) float f32x4;

__device__ __forceinline__ unsigned short f2bf(float f) {
    unsigned u = __float_as_uint(f);
    u += 0x7FFFu + ((u >> 16) & 1u);   // RNE
    return (unsigned short)(u >> 16);
}
__device__ __forceinline__ float bf2f(unsigned short h) {
    return __uint_as_float(((unsigned)h) << 16);
}
__device__ __forceinline__ float gmask(int k) {
    float t = ((float)k - 1024.0f) * (1.0f / 512.0f);
    return expf(-0.5f * t * t);
}

__device__ __forceinline__ void glds16(const unsigned short* gp, unsigned short* lp) {
    __builtin_amdgcn_global_load_lds((const __attribute__((address_space(1))) void*)gp,
                                     (__attribute__((address_space(3))) void*)lp, 16, 0, 0);
}

// Stage a 128x32 bf16 tile (row-major, 32 elems/row, XOR seg-swizzled) from
// global (row stride ldK elements) into lds[128*32]. Wave w covers rows
// [32w,32w+32). LDS slot for lane l is forced to base + l*16B (global_load_lds),
// so the swizzle is applied by permuting WHICH global 16B chunk each lane loads:
// slot (row, s) holds global seg s ^ ((row>>1)&3)  -> conflict-free ds_read_b128.
__device__ __forceinline__ void stage_tile(const unsigned short* __restrict__ g, int ldK,
                                           unsigned short* lds, int wave, int lane) {
    int row = wave * 32 + (lane >> 2);
    int seg = (lane & 3) ^ ((row >> 1) & 3);
    const unsigned short* gp = g + (long)row * ldK + seg * 8;
    unsigned short* lp = lds + wave * 1024;
    glds16(gp, lp);
    // row+16: (row>>1)&3 unchanged -> same seg
    glds16(gp + 16 * (long)ldK, lp + 512);
}

enum { OUT_F32 = 0, OUT_BF16 = 1, OUT_SPLIT = 2, OUT_BF16T = 3 };

// C[M,N] = scale * (A @ B^T) [* gmask(col)] [+ bias(col)]
// A: [M,K] row-major bf16 (hi, + lo if SPLIT). B: [N,K] row-major bf16 (hi/lo).
// SPLIT computes Ah*Bh + Ah*Bl + Al*Bh (drops lo*lo; ~fp32 accuracy).
// OUT_BF16T writes C transposed as [B][N][SEQ] (V^T), M = B*SEQ.
template <bool SPLIT, bool MASK, bool BIAS, int OUT>
__global__ __launch_bounds__(256, 2) void mfma_gemm(
    const unsigned short* __restrict__ Ah, const unsigned short* __restrict__ Al,
    const unsigned short* __restrict__ Bh, const unsigned short* __restrict__ Bl,
    const float* __restrict__ bias,
    float* __restrict__ Cf, unsigned short* __restrict__ Ch, unsigned short* __restrict__ Cl,
    int M, int N, int K, float scale,
    long sA, long sB, long sC)
{
    __shared__ unsigned short AsH[128 * 32];
    __shared__ unsigned short BsH[128 * 32];
    __shared__ unsigned short AsL[SPLIT ? 128 * 32 : 64];
    __shared__ unsigned short BsL[SPLIT ? 128 * 32 : 64];

    const int bz = blockIdx.z;
    const int tid = threadIdx.x;
    const int wave = tid >> 6;
    const int lane = tid & 63;
    const int wm = (wave & 1) * 64;
    const int wn = (wave >> 1) * 64;
    const long m0 = (long)blockIdx.y * 128;
    const long n0 = (long)blockIdx.x * 128;
    const int lm = lane & 15;     // row (A) / col (B) within 16-tile
    const int lk = lane >> 4;     // k-quad: k = lk*8 + j

    const unsigned short* pAh = Ah + bz * sA + m0 * K;
    const unsigned short* pBh = Bh + bz * sB + n0 * K;
    const unsigned short* pAl = SPLIT ? (Al + bz * sA + m0 * K) : (const unsigned short*)nullptr;
    const unsigned short* pBl = SPLIT ? (Bl + bz * sB + n0 * K) : (const unsigned short*)nullptr;

    f32x4 acc[4][4];
#pragma unroll
    for (int i = 0; i < 4; ++i)
#pragma unroll
        for (int j = 0; j < 4; ++j) {
            acc[i][j].x = 0.f; acc[i][j].y = 0.f; acc[i][j].z = 0.f; acc[i][j].w = 0.f;
        }

    // per-lane LDS fragment offsets (K-loop invariant), swizzle applied
    int aoff[4], boff[4];
#pragma unroll
    for (int i = 0; i < 4; ++i) {
        int ar = wm + i * 16 + lm;
        aoff[i] = ar * 32 + ((lk ^ ((ar >> 1) & 3)) << 3);
        int br = wn + i * 16 + lm;
        boff[i] = br * 32 + ((lk ^ ((br >> 1) & 3)) << 3);
    }

    for (int k0 = 0; k0 < K; k0 += 32) {
        stage_tile(pAh + k0, K, AsH, wave, lane);
        stage_tile(pBh + k0, K, BsH, wave, lane);
        if (SPLIT) {
            stage_tile(pAl + k0, K, AsL, wave, lane);
            stage_tile(pBl + k0, K, BsL, wave, lane);
        }
        __syncthreads();

        short8 a_h[4], b_h[4];
#pragma unroll
        for (int i = 0; i < 4; ++i) a_h[i] = *(const short8*)((const short*)AsH + aoff[i]);
#pragma unroll
        for (int j = 0; j < 4; ++j) b_h[j] = *(const short8*)((const short*)BsH + boff[j]);

#pragma unroll
        for (int i = 0; i < 4; ++i)
#pragma unroll
            for (int j = 0; j < 4; ++j)
                acc[i][j] = __builtin_amdgcn_mfma_f32_16x16x32_bf16(a_h[i], b_h[j], acc[i][j], 0, 0, 0);

        if (SPLIT) {
            short8 a_l[4], b_l[4];
#pragma unroll
            for (int i = 0; i < 4; ++i) a_l[i] = *(const short8*)((const short*)AsL + aoff[i]);
#pragma unroll
            for (int j = 0; j < 4; ++j) b_l[j] = *(const short8*)((const short*)BsL + boff[j]);
#pragma unroll
            for (int i = 0; i < 4; ++i)
#pragma unroll
                for (int j = 0; j < 4; ++j)
                    acc[i][j] = __builtin_amdgcn_mfma_f32_16x16x32_bf16(a_h[i], b_l[j], acc[i][j], 0, 0, 0);
#pragma unroll
            for (int i = 0; i < 4; ++i)
#pragma unroll
                for (int j = 0; j < 4; ++j)
                    acc[i][j] = __builtin_amdgcn_mfma_f32_16x16x32_bf16(a_l[i], b_h[j], acc[i][j], 0, 0, 0);
        }
        __syncthreads();
    }

    // epilogue: C/D layout col = lane&15, row = (lane>>4)*4 + r  [m89/m91]
    float* cF = (OUT == OUT_F32) ? (Cf + bz * sC) : (float*)nullptr;
    unsigned short* cH = (OUT != OUT_F32) ? (Ch + bz * sC) : (unsigned short*)nullptr;
    unsigned short* cL = (OUT == OUT_SPLIT) ? (Cl + bz * sC) : (unsigned short*)nullptr;
#pragma unroll
    for (int i = 0; i < 4; ++i) {
        long mrow = m0 + wm + i * 16 + lk * 4;
#pragma unroll
        for (int j = 0; j < 4; ++j) {
            int n = (int)n0 + wn + j * 16 + lm;
            float mult = MASK ? scale * gmask(n) : scale;
            float bs = BIAS ? bias[n] : 0.0f;
            float v[4];
#pragma unroll
            for (int r = 0; r < 4; ++r) v[r] = acc[i][j][r] * mult + bs;
            if (OUT == OUT_F32) {
#pragma unroll
                for (int r = 0; r < 4; ++r) cF[(mrow + r) * N + n] = v[r];
            } else if (OUT == OUT_BF16) {
#pragma unroll
                for (int r = 0; r < 4; ++r) cH[(mrow + r) * N + n] = f2bf(v[r]);
            } else if (OUT == OUT_SPLIT) {
#pragma unroll
                for (int r = 0; r < 4; ++r) {
                    long idx = (mrow + r) * N + n;
                    unsigned short h = f2bf(v[r]);
                    cH[idx] = h;
                    cL[idx] = f2bf(v[r] - bf2f(h));
                }
            } else {  // OUT_BF16T: V^T layout [batch][N][SEQ]; m = b*SEQ + s
                long b = mrow >> 11;          // SEQ = 2048 = 2^11
                long s = mrow & 2047;
                long idx0 = b * (long)DIM * SEQ + (long)n * SEQ + s;  // 4 consecutive s
                unsigned long long pk =
                    (unsigned long long)f2bf(v[0]) |
                    ((unsigned long long)f2bf(v[1]) << 16) |
                    ((unsigned long long)f2bf(v[2]) << 32) |
                    ((unsigned long long)f2bf(v[3]) << 48);
                *(unsigned long long*)(cH + idx0) = pk;
            }
        }
    }
}

// row softmax: fp32 in, bf16 out. grid (SEQ, B), 256 thr, 8 elems/thr.
__global__ __launch_bounds__(256) void softmax_rows(const float* __restrict__ Sc,
                                                    unsigned short* __restrict__ P)
{
    long base = ((long)blockIdx.y * SEQ + blockIdx.x) * SEQ;
    const int tid = threadIdx.x;
    float v[8];
    float mx = -1e30f;
#pragma unroll
    for (int i = 0; i < 8; ++i) {
        v[i] = Sc[base + i * 256 + tid];
        mx = fmaxf(mx, v[i]);
    }
#pragma unroll
    for (int off = 32; off > 0; off >>= 1) mx = fmaxf(mx, __shfl_down(mx, off));
    __shared__ float redm[4], reds[4];
    if ((tid & 63) == 0) redm[tid >> 6] = mx;
    __syncthreads();
    mx = fmaxf(fmaxf(redm[0], redm[1]), fmaxf(redm[2], redm[3]));
    float s = 0.f;
#pragma unroll
    for (int i = 0; i < 8; ++i) { v[i] = expf(v[i] - mx); s += v[i]; }
#pragma unroll
    for (int off = 32; off > 0; off >>= 1) s += __shfl_down(s, off);
    if ((tid & 63) == 0) reds[tid >> 6] = s;
    __syncthreads();
    s = reds[0] + reds[1] + reds[2] + reds[3];
    float inv = 1.f / s;
#pragma unroll
    for (int i = 0; i < 8; ++i) P[base + i * 256 + tid] = f2bf(v[i] * inv);
}

// fp32 -> bf16 hi + lo (residual), vectorized x4
__global__ __launch_bounds__(256) void split_f32(const float* __restrict__ src,
    unsigned short* __restrict__ hi, unsigned short* __restrict__ lo, long n)
{
    long i = ((long)blockIdx.x * 256 + threadIdx.x) * 4;
    long stride = (long)gridDim.x * 1024;
    for (; i < n; i += stride) {
        float4 v = *(const float4*)(src + i);
        unsigned short h0 = f2bf(v.x), h1 = f2bf(v.y), h2 = f2bf(v.z), h3 = f2bf(v.w);
        unsigned long long ph = (unsigned long long)h0 | ((unsigned long long)h1 << 16) |
                                ((unsigned long long)h2 << 32) | ((unsigned long long)h3 << 48);
        *(unsigned long long*)(hi + i) = ph;
        unsigned short l0 = f2bf(v.x - bf2f(h0)), l1 = f2bf(v.y - bf2f(h1));
        unsigned short l2 = f2bf(v.z - bf2f(h2)), l3 = f2bf(v.w - bf2f(h3));
        unsigned long long pl = (unsigned long long)l0 | ((unsigned long long)l1 << 16) |
                                ((unsigned long long)l2 << 32) | ((unsigned long long)l3 << 48);
        *(unsigned long long*)(lo + i) = pl;
    }
}

__global__ __launch_bounds__(256) void cvt_bf16(const float* __restrict__ src,
    unsigned short* __restrict__ dst, long n)
{
    long i = ((long)blockIdx.x * 256 + threadIdx.x) * 4;
    long stride = (long)gridDim.x * 1024;
    for (; i < n; i += stride) {
        float4 v = *(const float4*)(src + i);
        unsigned long long ph = (unsigned long long)f2bf(v.x) | ((unsigned long long)f2bf(v.y) << 16) |
                                ((unsigned long long)f2bf(v.z) << 32) | ((unsigned long long)f2bf(v.w) << 48);
        *(unsigned long long*)(dst + i) = ph;
    }
}

extern "C" void kernel_launch(void* const* d_in, const int* in_sizes, int n_in,
                              void* d_out, int out_size, void* d_ws, size_t ws_size,
                              hipStream_t stream)
{
    const float* x  = (const float*)d_in[0];
    const float* Wq = (const float*)d_in[1];
    const float* bq = (const float*)d_in[2];
    const float* Wk = (const float*)d_in[3];
    const float* bk = (const float*)d_in[4];
    const float* Wv = (const float*)d_in[5];
    const float* bv = (const float*)d_in[6];
    const float* Wo = (const float*)d_in[7];
    const float* bo = (const float*)d_in[8];
    float* out = (float*)d_out;

    const long MD = 4L * SEQ * DIM;    // 8M elems (B*S*D)
    const long WW = (long)DIM * DIM;   // 1M
    // workspace layout (188 MB total):
    unsigned short* xh  = (unsigned short*)d_ws;   // 16 MB
    unsigned short* xl  = xh + MD;                 // 16 MB
    unsigned short* Wqh = xl + MD;                 // 2 MB each
    unsigned short* Wql = Wqh + WW;
    unsigned short* Wkh = Wql + WW;
    unsigned short* Wkl = Wkh + WW;
    unsigned short* Wvh = Wkl + WW;
    unsigned short* Woh = Wvh + WW;
    unsigned short* Qh  = Woh + WW;                // 16 MB each
    unsigned short* Ql  = Qh + MD;
    unsigned short* Kh  = Ql + MD;
    unsigned short* Kl  = Kh + MD;
    unsigned short* VT  = Kl + MD;                 // 16 MB, [B][D][S]
    float* Sc = (float*)(VT + MD);                 // 64 MB
    unsigned short* P  = Qh;   // alias: Qh/Ql dead after scores GEMM (32 MB)
    unsigned short* O1 = Kh;   // alias: Kh dead after scores GEMM (16 MB)

    dim3 blk(256);
    split_f32<<<1024, blk, 0, stream>>>(x, xh, xl, MD);
    split_f32<<<256, blk, 0, stream>>>(Wq, Wqh, Wql, WW);
    split_f32<<<256, blk, 0, stream>>>(Wk, Wkh, Wkl, WW);
    cvt_bf16<<<256, blk, 0, stream>>>(Wv, Wvh, WW);
    cvt_bf16<<<256, blk, 0, stream>>>(Wo, Woh, WW);

    const long SD = (long)SEQ * DIM, SS = (long)SEQ * SEQ;

    // Q,K: split x @ split W^T + b -> stored split (hi/lo)
    mfma_gemm<true, false, true, OUT_SPLIT><<<dim3(DIM/128, (4*SEQ)/128, 1), blk, 0, stream>>>(
        xh, xl, Wqh, Wql, bq, nullptr, Qh, Ql, 4*SEQ, DIM, DIM, 1.0f, 0, 0, 0);
    mfma_gemm<true, false, true, OUT_SPLIT><<<dim3(DIM/128, (4*SEQ)/128, 1), blk, 0, stream>>>(
        xh, xl, Wkh, Wkl, bk, nullptr, Kh, Kl, 4*SEQ, DIM, DIM, 1.0f, 0, 0, 0);
    // V: plain bf16, epilogue writes V^T [B][D][S]
    mfma_gemm<false, false, true, OUT_BF16T><<<dim3(DIM/128, (4*SEQ)/128, 1), blk, 0, stream>>>(
        xh, nullptr, Wvh, nullptr, bv, nullptr, VT, nullptr, 4*SEQ, DIM, DIM, 1.0f, 0, 0, 0);
    // scores: split Q @ split K^T * (1/32) * gmask(col) -> fp32
    mfma_gemm<true, true, false, OUT_F32><<<dim3(SEQ/128, SEQ/128, 4), blk, 0, stream>>>(
        Qh, Ql, Kh, Kl, nullptr, Sc, nullptr, nullptr, SEQ, SEQ, DIM, 0.03125f, SD, SD, SS);
    softmax_rows<<<dim3(SEQ, 4), blk, 0, stream>>>(Sc, P);
    // O1 = P @ (V^T)^T, plain bf16
    mfma_gemm<false, false, false, OUT_BF16><<<dim3(DIM/128, SEQ/128, 4), blk, 0, stream>>>(
        P, nullptr, VT, nullptr, nullptr, nullptr, O1, nullptr, SEQ, DIM, SEQ, 1.0f, SS, (long)DIM*SEQ, SD);
    // out = O1 @ Wo^T + bo -> fp32
    mfma_gemm<false, false, true, OUT_F32><<<dim3(DIM/128, (4*SEQ)/128, 1), blk, 0, stream>>>(
        O1, nullptr, Woh, nullptr, bo, out, nullptr, nullptr, 4*SEQ, DIM, DIM, 1.0f, 0, 0, 0);
}

// Round 3
// 348.846 us; speedup vs baseline: 4.9638x; 1.4018x over previous
//
#include <hip/hip_runtime.h>
#include <math.h>

#define SEQ   2048
#define DIM   1024

typedef __attribute__((ext_vector_type(8))) _Float16 half8;
typedef __attribute__((ext_vector_type(4))) float f32x4;

__device__ __forceinline__ unsigned short f2h(float f) {
    _Float16 h = (_Float16)f;          // RNE
    union { _Float16 h; unsigned short u; } c; c.h = h;
    return c.u;
}
__device__ __forceinline__ float gmask(int k) {
    float t = ((float)k - 1024.0f) * (1.0f / 512.0f);
    return expf(-0.5f * t * t);
}

__device__ __forceinline__ void glds16(const unsigned short* gp, unsigned short* lp) {
    __builtin_amdgcn_global_load_lds((const __attribute__((address_space(1))) void*)gp,
                                     (__attribute__((address_space(3))) void*)lp, 16, 0, 0);
}

// Stage a 128x32 fp16 tile (row-major, 32 elems/row, XOR seg-swizzled) from
// global (row stride ldK elements) into lds[128*32]. Wave w covers rows
// [32w,32w+32). LDS slot (row,s) holds global seg s ^ ((row>>1)&3)
// -> conflict-free ds_read_b128 on the fragment reads.
__device__ __forceinline__ void stage_tile(const unsigned short* __restrict__ g, int ldK,
                                           unsigned short* lds, int wave, int lane) {
    int row = wave * 32 + (lane >> 2);
    int seg = (lane & 3) ^ ((row >> 1) & 3);
    const unsigned short* gp = g + (long)row * ldK + seg * 8;
    unsigned short* lp = lds + wave * 1024;
    glds16(gp, lp);
    glds16(gp + 16 * (long)ldK, lp + 512);   // row+16: same swizzle phase
}

enum { OUT_F32 = 0, OUT_F16 = 1, OUT_F16T = 2 };

// C[M,N] = scale * (A @ B^T) [* gmask(col)] [+ bias(col)]
// A: [M,K] row-major fp16. B: [N,K] row-major fp16. fp32 MFMA accumulate.
// OUT_F16T writes C transposed as [B][N][SEQ] (V^T), M = B*SEQ.
template <bool MASK, bool BIAS, int OUT>
__global__ __launch_bounds__(256, 2) void mfma_gemm(
    const unsigned short* __restrict__ A, const unsigned short* __restrict__ Bm,
    const float* __restrict__ bias,
    float* __restrict__ Cf, unsigned short* __restrict__ Ch,
    int M, int N, int K, float scale,
    long sA, long sB, long sC)
{
    __shared__ unsigned short As[128 * 32];
    __shared__ unsigned short Bs[128 * 32];

    const int bz = blockIdx.z;
    const int tid = threadIdx.x;
    const int wave = tid >> 6;
    const int lane = tid & 63;
    const int wm = (wave & 1) * 64;
    const int wn = (wave >> 1) * 64;
    const long m0 = (long)blockIdx.y * 128;
    const long n0 = (long)blockIdx.x * 128;
    const int lm = lane & 15;     // row (A) / col (B) within 16-tile
    const int lk = lane >> 4;     // k-quad

    const unsigned short* pA = A + bz * sA + m0 * K;
    const unsigned short* pB = Bm + bz * sB + n0 * K;

    f32x4 acc[4][4];
#pragma unroll
    for (int i = 0; i < 4; ++i)
#pragma unroll
        for (int j = 0; j < 4; ++j) {
            acc[i][j].x = 0.f; acc[i][j].y = 0.f; acc[i][j].z = 0.f; acc[i][j].w = 0.f;
        }

    // per-lane LDS fragment offsets (K-loop invariant), swizzle applied
    int aoff[4], boff[4];
#pragma unroll
    for (int i = 0; i < 4; ++i) {
        int ar = wm + i * 16 + lm;
        aoff[i] = ar * 32 + ((lk ^ ((ar >> 1) & 3)) << 3);
        int br = wn + i * 16 + lm;
        boff[i] = br * 32 + ((lk ^ ((br >> 1) & 3)) << 3);
    }

    for (int k0 = 0; k0 < K; k0 += 32) {
        stage_tile(pA + k0, K, As, wave, lane);
        stage_tile(pB + k0, K, Bs, wave, lane);
        __syncthreads();

        half8 a[4], b[4];
#pragma unroll
        for (int i = 0; i < 4; ++i) a[i] = *(const half8*)((const short*)As + aoff[i]);
#pragma unroll
        for (int j = 0; j < 4; ++j) b[j] = *(const half8*)((const short*)Bs + boff[j]);

#pragma unroll
        for (int i = 0; i < 4; ++i)
#pragma unroll
            for (int j = 0; j < 4; ++j)
                acc[i][j] = __builtin_amdgcn_mfma_f32_16x16x32_f16(a[i], b[j], acc[i][j], 0, 0, 0);
        __syncthreads();
    }

    // epilogue: C/D layout col = lane&15, row = (lane>>4)*4 + r  [m89/m91]
    float* cF = (OUT == OUT_F32) ? (Cf + bz * sC) : (float*)nullptr;
    unsigned short* cH = (OUT != OUT_F32) ? (Ch + bz * sC) : (unsigned short*)nullptr;
#pragma unroll
    for (int i = 0; i < 4; ++i) {
        long mrow = m0 + wm + i * 16 + lk * 4;
#pragma unroll
        for (int j = 0; j < 4; ++j) {
            int n = (int)n0 + wn + j * 16 + lm;
            float mult = MASK ? scale * gmask(n) : scale;
            float bs = BIAS ? bias[n] : 0.0f;
            float v[4];
#pragma unroll
            for (int r = 0; r < 4; ++r) v[r] = acc[i][j][r] * mult + bs;
            if (OUT == OUT_F32) {
#pragma unroll
                for (int r = 0; r < 4; ++r) cF[(mrow + r) * N + n] = v[r];
            } else if (OUT == OUT_F16) {
#pragma unroll
                for (int r = 0; r < 4; ++r) cH[(mrow + r) * N + n] = f2h(v[r]);
            } else {  // OUT_F16T: V^T layout [batch][N][SEQ]; m = b*SEQ + s
                long b = mrow >> 11;          // SEQ = 2048 = 2^11
                long s = mrow & 2047;
                long idx0 = b * (long)DIM * SEQ + (long)n * SEQ + s;  // 4 consecutive s
                unsigned long long pk =
                    (unsigned long long)f2h(v[0]) |
                    ((unsigned long long)f2h(v[1]) << 16) |
                    ((unsigned long long)f2h(v[2]) << 32) |
                    ((unsigned long long)f2h(v[3]) << 48);
                *(unsigned long long*)(cH + idx0) = pk;
            }
        }
    }
}

// row softmax: fp32 in, fp16 out. grid (SEQ, B), 256 thr, 8 elems/thr.
__global__ __launch_bounds__(256) void softmax_rows(const float* __restrict__ Sc,
                                                    unsigned short* __restrict__ P)
{
    long base = ((long)blockIdx.y * SEQ + blockIdx.x) * SEQ;
    const int tid = threadIdx.x;
    float v[8];
    float mx = -1e30f;
#pragma unroll
    for (int i = 0; i < 8; ++i) {
        v[i] = Sc[base + i * 256 + tid];
        mx = fmaxf(mx, v[i]);
    }
#pragma unroll
    for (int off = 32; off > 0; off >>= 1) mx = fmaxf(mx, __shfl_down(mx, off));
    __shared__ float redm[4], reds[4];
    if ((tid & 63) == 0) redm[tid >> 6] = mx;
    __syncthreads();
    mx = fmaxf(fmaxf(redm[0], redm[1]), fmaxf(redm[2], redm[3]));
    float s = 0.f;
#pragma unroll
    for (int i = 0; i < 8; ++i) { v[i] = expf(v[i] - mx); s += v[i]; }
#pragma unroll
    for (int off = 32; off > 0; off >>= 1) s += __shfl_down(s, off);
    if ((tid & 63) == 0) reds[tid >> 6] = s;
    __syncthreads();
    s = reds[0] + reds[1] + reds[2] + reds[3];
    float inv = 1.f / s;
#pragma unroll
    for (int i = 0; i < 8; ++i) P[base + i * 256 + tid] = f2h(v[i] * inv);
}

// fp32 -> fp16, vectorized x4
__global__ __launch_bounds__(256) void cvt_f16(const float* __restrict__ src,
    unsigned short* __restrict__ dst, long n)
{
    long i = ((long)blockIdx.x * 256 + threadIdx.x) * 4;
    long stride = (long)gridDim.x * 1024;
    for (; i < n; i += stride) {
        float4 v = *(const float4*)(src + i);
        unsigned long long p = (unsigned long long)f2h(v.x) | ((unsigned long long)f2h(v.y) << 16) |
                               ((unsigned long long)f2h(v.z) << 32) | ((unsigned long long)f2h(v.w) << 48);
        *(unsigned long long*)(dst + i) = p;
    }
}

extern "C" void kernel_launch(void* const* d_in, const int* in_sizes, int n_in,
                              void* d_out, int out_size, void* d_ws, size_t ws_size,
                              hipStream_t stream)
{
    const float* x  = (const float*)d_in[0];
    const float* Wq = (const float*)d_in[1];
    const float* bq = (const float*)d_in[2];
    const float* Wk = (const float*)d_in[3];
    const float* bk = (const float*)d_in[4];
    const float* Wv = (const float*)d_in[5];
    const float* bv = (const float*)d_in[6];
    const float* Wo = (const float*)d_in[7];
    const float* bo = (const float*)d_in[8];
    float* out = (float*)d_out;

    const long MD = 4L * SEQ * DIM;    // 8M elems (B*S*D)
    const long WW = (long)DIM * DIM;   // 1M
    // workspace layout (136 MB):
    unsigned short* xh  = (unsigned short*)d_ws;   // 16 MB
    unsigned short* Wqh = xh + MD;                 // 2 MB each
    unsigned short* Wkh = Wqh + WW;
    unsigned short* Wvh = Wkh + WW;
    unsigned short* Woh = Wvh + WW;
    unsigned short* Qh  = Woh + WW;                // 16 MB
    unsigned short* Kh  = Qh + MD;                 // 16 MB (contiguous with Qh)
    unsigned short* VT  = Kh + MD;                 // 16 MB, [B][D][S]
    float* Sc = (float*)(VT + MD);                 // 64 MB
    unsigned short* P  = Qh;   // alias: Qh+Kh (32 MB) dead after scores GEMM
    unsigned short* O1 = xh;   // alias: x dead after V projection

    dim3 blk(256);
    cvt_f16<<<1024, blk, 0, stream>>>(x, xh, MD);
    cvt_f16<<<256, blk, 0, stream>>>(Wq, Wqh, WW);
    cvt_f16<<<256, blk, 0, stream>>>(Wk, Wkh, WW);
    cvt_f16<<<256, blk, 0, stream>>>(Wv, Wvh, WW);
    cvt_f16<<<256, blk, 0, stream>>>(Wo, Woh, WW);

    const long SD = (long)SEQ * DIM, SS = (long)SEQ * SEQ;

    // Q,K,V projections: [B*S, D] = x @ W^T + b
    mfma_gemm<false, true, OUT_F16><<<dim3(DIM/128, (4*SEQ)/128, 1), blk, 0, stream>>>(
        xh, Wqh, bq, nullptr, Qh, 4*SEQ, DIM, DIM, 1.0f, 0, 0, 0);
    mfma_gemm<false, true, OUT_F16><<<dim3(DIM/128, (4*SEQ)/128, 1), blk, 0, stream>>>(
        xh, Wkh, bk, nullptr, Kh, 4*SEQ, DIM, DIM, 1.0f, 0, 0, 0);
    mfma_gemm<false, true, OUT_F16T><<<dim3(DIM/128, (4*SEQ)/128, 1), blk, 0, stream>>>(
        xh, Wvh, bv, nullptr, VT, 4*SEQ, DIM, DIM, 1.0f, 0, 0, 0);
    // scores: Q @ K^T * (1/32) * gmask(col) -> fp32
    mfma_gemm<true, false, OUT_F32><<<dim3(SEQ/128, SEQ/128, 4), blk, 0, stream>>>(
        Qh, Kh, nullptr, Sc, nullptr, SEQ, SEQ, DIM, 0.03125f, SD, SD, SS);
    softmax_rows<<<dim3(SEQ, 4), blk, 0, stream>>>(Sc, P);
    // O1 = P @ (V^T)^T
    mfma_gemm<false, false, OUT_F16><<<dim3(DIM/128, SEQ/128, 4), blk, 0, stream>>>(
        P, VT, nullptr, nullptr, O1, SEQ, DIM, SEQ, 1.0f, SS, (long)DIM*SEQ, SD);
    // out = O1 @ Wo^T + bo -> fp32
    mfma_gemm<false, true, OUT_F32><<<dim3(DIM/128, (4*SEQ)/128, 1), blk, 0, stream>>>(
        O1, Woh, bo, out, nullptr, 4*SEQ, DIM, DIM, 1.0f, 0, 0, 0);
}

// Round 4
// 295.399 us; speedup vs baseline: 5.8620x; 1.1809x over previous
//
#include <hip/hip_runtime.h>
#include <math.h>

#define SEQ 2048
#define DIM 1024

typedef __attribute__((ext_vector_type(8))) _Float16 half8;
typedef __attribute__((ext_vector_type(4))) float f32x4;

__device__ __forceinline__ unsigned short f2h(float f) {
    union { _Float16 h; unsigned short u; } c; c.h = (_Float16)f;
    return c.u;
}
__device__ __forceinline__ float gmask(int k) {
    float t = ((float)k - 1024.0f) * (1.0f / 512.0f);
    return expf(-0.5f * t * t);
}
__device__ __forceinline__ void glds16(const unsigned short* gp, unsigned short* lp) {
    __builtin_amdgcn_global_load_lds((const __attribute__((address_space(1))) void*)gp,
                                     (__attribute__((address_space(3))) void*)lp, 16, 0, 0);
}

// Stage a 128x64 fp16 tile (16 KB) from global (row stride ldK) into lds.
// LDS layout: row r at r*64 elems; 16B slot t at +t*8; slot t holds global
// seg t ^ (r&7)  -> conflict-free (2-way) ds_read_b128 fragment reads.
// Wave w covers rows [32w,32w+32); 4 glds calls of 1 KB each.
// global_load_lds dest = wave-uniform base + lane*16B: call c, lane l writes
// row 32w+8c+(l>>3), slot l&7; so lane fetches seg (l&7)^(l>>3) of its row.
__device__ __forceinline__ void stage64(const unsigned short* __restrict__ g, int ldK,
                                        unsigned short* lds, int wave, int lane) {
    int row = wave * 32 + (lane >> 3);
    int seg = (lane & 7) ^ (lane >> 3);
    const unsigned short* gp = g + (long)row * ldK + seg * 8;
    unsigned short* lp = lds + wave * 2048;
    glds16(gp, lp);
    glds16(gp + 8 * (long)ldK, lp + 512);
    glds16(gp + 16 * (long)ldK, lp + 1024);
    glds16(gp + 24 * (long)ldK, lp + 1536);
}

enum { EPI_QKV = 0, EPI_EXP = 1, EPI_PV = 2, EPI_OUT = 3 };

// C = A @ B^T epilogue-variant GEMM. A:[M,K] fp16 row-major, B:[N,K] fp16.
// EPI_QKV: N=3072 packed; writes Q[m][n], K[m][n], V^T[b][d][s] (+bias).
// EPI_EXP: writes fp16 exp(acc*scale*gmask(n))  (unnormalized softmax numer).
// EPI_PV : writes fp16 acc * rs[row]            (softmax denominator).
// EPI_OUT: writes fp32 acc + bias(n).
template <int EPI>
__global__ __launch_bounds__(256, 2) void mfma_gemm(
    const unsigned short* __restrict__ A, const unsigned short* __restrict__ Bm,
    const float* __restrict__ bias, const float* __restrict__ rs,
    float* __restrict__ Cf, unsigned short* __restrict__ Ch,
    int M, int N, int K, float scale, long sA, long sB, long sC)
{
    __shared__ unsigned short As[128 * 64];
    __shared__ unsigned short Bs[128 * 64];

    const int bz = blockIdx.z;
    const int tid = threadIdx.x;
    const int wave = tid >> 6;
    const int lane = tid & 63;
    const int wm = (wave & 1) * 64;
    const int wn = (wave >> 1) * 64;
    const long m0 = (long)blockIdx.y * 128;
    const long n0 = (long)blockIdx.x * 128;
    const int lm = lane & 15;
    const int lk = lane >> 4;

    const unsigned short* pA = A + bz * sA + m0 * K;
    const unsigned short* pB = Bm + bz * sB + n0 * K;

    f32x4 acc[4][4];
#pragma unroll
    for (int i = 0; i < 4; ++i)
#pragma unroll
        for (int j = 0; j < 4; ++j) {
            acc[i][j].x = 0.f; acc[i][j].y = 0.f; acc[i][j].z = 0.f; acc[i][j].w = 0.f;
        }

    // fragment LDS offsets (elems), swizzle applied: frag (i, kstep t)
    int aoff[4][2], boff[4][2];
#pragma unroll
    for (int i = 0; i < 4; ++i)
#pragma unroll
        for (int t = 0; t < 2; ++t) {
            int ar = wm + i * 16 + lm;
            aoff[i][t] = ar * 64 + (((4 * t + lk) ^ (ar & 7)) << 3);
            int br = wn + i * 16 + lm;
            boff[i][t] = br * 64 + (((4 * t + lk) ^ (br & 7)) << 3);
        }

    for (int k0 = 0; k0 < K; k0 += 64) {
        stage64(pA + k0, K, As, wave, lane);
        stage64(pB + k0, K, Bs, wave, lane);
        __syncthreads();
#pragma unroll
        for (int t = 0; t < 2; ++t) {
            half8 a[4], b[4];
#pragma unroll
            for (int i = 0; i < 4; ++i) a[i] = *(const half8*)(As + aoff[i][t]);
#pragma unroll
            for (int j = 0; j < 4; ++j) b[j] = *(const half8*)(Bs + boff[j][t]);
#pragma unroll
            for (int i = 0; i < 4; ++i)
#pragma unroll
                for (int j = 0; j < 4; ++j)
                    acc[i][j] = __builtin_amdgcn_mfma_f32_16x16x32_f16(a[i], b[j], acc[i][j], 0, 0, 0);
        }
        __syncthreads();
    }

    // ---- epilogue. C/D layout: col = lane&15, row = (lane>>4)*4 + r
    const long MD = 8388608;  // 4*SEQ*DIM
    const float* rsb = (EPI == EPI_PV) ? rs + bz * SEQ : (const float*)nullptr;
    float* cF = (EPI == EPI_OUT) ? Cf + bz * sC : (float*)nullptr;
    unsigned short* cH = (EPI != EPI_OUT) ? Ch + bz * sC : (unsigned short*)nullptr;

#pragma unroll
    for (int i = 0; i < 4; ++i) {
        long mrow = m0 + wm + i * 16 + lk * 4;
        float rs4[4];
        if (EPI == EPI_PV) {
#pragma unroll
            for (int r = 0; r < 4; ++r) rs4[r] = rsb[mrow + r];
        }
#pragma unroll
        for (int j = 0; j < 4; ++j) {
            int n = (int)n0 + wn + j * 16 + lm;
            if (EPI == EPI_QKV) {
                int sel = n >> 10;          // block-uniform (128 | 1024)
                int n1 = n & 1023;
                float bs = bias[n];
                if (sel < 2) {
                    unsigned short* dst = cH + (long)sel * MD;
#pragma unroll
                    for (int r = 0; r < 4; ++r)
                        dst[(mrow + r) * (long)DIM + n1] = f2h(acc[i][j][r] + bs);
                } else {
                    long b = mrow >> 11, s = mrow & 2047;
                    long idx = 2 * MD + b * (long)DIM * SEQ + (long)n1 * SEQ + s;
                    unsigned long long pk =
                        (unsigned long long)f2h(acc[i][j].x + bs) |
                        ((unsigned long long)f2h(acc[i][j].y + bs) << 16) |
                        ((unsigned long long)f2h(acc[i][j].z + bs) << 32) |
                        ((unsigned long long)f2h(acc[i][j].w + bs) << 48);
                    *(unsigned long long*)(cH + idx) = pk;
                }
            } else if (EPI == EPI_EXP) {
                float mult = scale * gmask(n);
#pragma unroll
                for (int r = 0; r < 4; ++r)
                    cH[(mrow + r) * (long)N + n] = f2h(expf(acc[i][j][r] * mult));
            } else if (EPI == EPI_PV) {
#pragma unroll
                for (int r = 0; r < 4; ++r)
                    cH[(mrow + r) * (long)N + n] = f2h(acc[i][j][r] * rs4[r]);
            } else {  // EPI_OUT
                float bs = bias[n];
#pragma unroll
                for (int r = 0; r < 4; ++r)
                    cF[(mrow + r) * (long)N + n] = acc[i][j][r] + bs;
            }
        }
    }
}

// per-row sum of fp16 expS -> invrs = 1/sum. grid (SEQ, B), 256 thr.
__global__ __launch_bounds__(256) void rowsum(const unsigned short* __restrict__ E,
                                              float* __restrict__ invrs)
{
    long base = ((long)blockIdx.y * SEQ + blockIdx.x) * SEQ;
    const int tid = threadIdx.x;
    half8 h = ((const half8*)(E + base))[tid];
    float s = 0.f;
#pragma unroll
    for (int i = 0; i < 8; ++i) s += (float)h[i];
#pragma unroll
    for (int off = 32; off > 0; off >>= 1) s += __shfl_down(s, off);
    __shared__ float red[4];
    if ((tid & 63) == 0) red[tid >> 6] = s;
    __syncthreads();
    if (tid == 0)
        invrs[(long)blockIdx.y * SEQ + blockIdx.x] = 1.0f / (red[0] + red[1] + red[2] + red[3]);
}

// fp32 -> fp16, vectorized x4, grid-stride
__global__ __launch_bounds__(256) void cvt_f16(const float* __restrict__ src,
    unsigned short* __restrict__ dst, long n)
{
    long i = ((long)blockIdx.x * 256 + threadIdx.x) * 4;
    long stride = (long)gridDim.x * 1024;
    for (; i < n; i += stride) {
        float4 v = *(const float4*)(src + i);
        unsigned long long p = (unsigned long long)f2h(v.x) | ((unsigned long long)f2h(v.y) << 16) |
                               ((unsigned long long)f2h(v.z) << 32) | ((unsigned long long)f2h(v.w) << 48);
        *(unsigned long long*)(dst + i) = p;
    }
}

// pack Wq|Wk|Wv|Wo (each 1M fp32) into one 4M fp16 buffer
__global__ __launch_bounds__(256) void pack_w4(const float* __restrict__ W0,
    const float* __restrict__ W1, const float* __restrict__ W2, const float* __restrict__ W3,
    unsigned short* __restrict__ dst)
{
    const long WW = 1048576;
    long i = ((long)blockIdx.x * 256 + threadIdx.x) * 4;   // grid exactly covers 4M
    int sel = (int)(i >> 20);
    const float* src = (sel == 0) ? W0 : (sel == 1) ? W1 : (sel == 2) ? W2 : W3;
    float4 v = *(const float4*)(src + (i & (WW - 1)));
    unsigned long long p = (unsigned long long)f2h(v.x) | ((unsigned long long)f2h(v.y) << 16) |
                           ((unsigned long long)f2h(v.z) << 32) | ((unsigned long long)f2h(v.w) << 48);
    *(unsigned long long*)(dst + i) = p;
}

// pack bq|bk|bv into bqkv[3072] fp32
__global__ __launch_bounds__(256) void pack_bias(const float* __restrict__ b0,
    const float* __restrict__ b1, const float* __restrict__ b2, float* __restrict__ dst)
{
    int i = blockIdx.x * 256 + threadIdx.x;   // grid = 12 blocks
    int sel = i >> 10;
    const float* src = (sel == 0) ? b0 : (sel == 1) ? b1 : b2;
    dst[i] = src[i & 1023];
}

extern "C" void kernel_launch(void* const* d_in, const int* in_sizes, int n_in,
                              void* d_out, int out_size, void* d_ws, size_t ws_size,
                              hipStream_t stream)
{
    const float* x  = (const float*)d_in[0];
    const float* Wq = (const float*)d_in[1];
    const float* bq = (const float*)d_in[2];
    const float* Wk = (const float*)d_in[3];
    const float* bk = (const float*)d_in[4];
    const float* Wv = (const float*)d_in[5];
    const float* bv = (const float*)d_in[6];
    const float* Wo = (const float*)d_in[7];
    const float* bo = (const float*)d_in[8];
    float* out = (float*)d_out;

    const long MD = 4L * SEQ * DIM;    // 8M
    const long WW = (long)DIM * DIM;   // 1M
    const long SD = (long)SEQ * DIM, SS = (long)SEQ * SEQ;

    unsigned short* xh   = (unsigned short*)d_ws;  // 16 MB
    unsigned short* Wp   = xh + MD;                // 8 MB (Wqkv 3M + Wo 1M fp16)
    unsigned short* Woh  = Wp + 3 * WW;
    float* bqkv          = (float*)(Wp + 4 * WW);  // 3072 (+pad to 4096)
    unsigned short* Qh   = (unsigned short*)(bqkv + 4096);  // Qh|Kh|VT contiguous, 48 MB
    unsigned short* Kh   = Qh + MD;
    unsigned short* VT   = Kh + MD;                // [B][D][S]
    unsigned short* expS = VT + MD;                // 16M elems, 32 MB
    float* invrs         = (float*)(expS + 4L * SEQ * SEQ);  // 8192 floats
    unsigned short* O1   = xh;                     // alias: x dead after QKV GEMM

    dim3 blk(256);
    cvt_f16<<<1024, blk, 0, stream>>>(x, xh, MD);
    pack_w4<<<4096, blk, 0, stream>>>(Wq, Wk, Wv, Wo, Wp);
    pack_bias<<<12, blk, 0, stream>>>(bq, bk, bv, bqkv);

    // QKV fused: [8192,3072] = x @ Wqkv^T + bqkv -> Q, K, V^T
    mfma_gemm<EPI_QKV><<<dim3(3 * DIM / 128, (4 * SEQ) / 128, 1), blk, 0, stream>>>(
        xh, Wp, bqkv, nullptr, nullptr, Qh, 4 * SEQ, 3 * DIM, DIM, 1.0f, 0, 0, 0);
    // scores -> expS = exp(QK^T/32 * gmask)
    mfma_gemm<EPI_EXP><<<dim3(SEQ / 128, SEQ / 128, 4), blk, 0, stream>>>(
        Qh, Kh, nullptr, nullptr, nullptr, expS, SEQ, SEQ, DIM, 0.03125f, SD, SD, SS);
    rowsum<<<dim3(SEQ, 4), blk, 0, stream>>>(expS, invrs);
    // O1 = (expS @ V) * invrs[row]
    mfma_gemm<EPI_PV><<<dim3(DIM / 128, SEQ / 128, 4), blk, 0, stream>>>(
        expS, VT, nullptr, invrs, nullptr, O1, SEQ, DIM, SEQ, 1.0f, SS, (long)DIM * SEQ, SD);
    // out = O1 @ Wo^T + bo (fp32)
    mfma_gemm<EPI_OUT><<<dim3(DIM / 128, (4 * SEQ) / 128, 1), blk, 0, stream>>>(
        O1, Woh, bo, nullptr, out, nullptr, 4 * SEQ, DIM, DIM, 1.0f, 0, 0, 0);
}